// Round 1
// baseline (1730.039 us; speedup 1.0000x reference)
//
#include <hip/hip_runtime.h>
#include <hip/hip_bf16.h>
#include <stdint.h>

#define NN 16384
#define KIN 512
#define COUT 256

typedef __attribute__((ext_vector_type(8))) short short8;
typedef __attribute__((ext_vector_type(4))) float floatx4;

__device__ __forceinline__ void llds16(const void* gp, void* lp) {
  __builtin_amdgcn_global_load_lds((const __attribute__((address_space(1))) void*)gp,
                                   (__attribute__((address_space(3))) void*)lp, 16, 0, 0);
}

__device__ __forceinline__ short8 cvt_bf16x8(floatx4 a, floatx4 b) {
  union { short8 v; __hip_bfloat162 h[4]; } u;
  u.h[0] = __float22bfloat162_rn(make_float2(a.x, a.y));
  u.h[1] = __float22bfloat162_rn(make_float2(a.z, a.w));
  u.h[2] = __float22bfloat162_rn(make_float2(b.x, b.y));
  u.h[3] = __float22bfloat162_rn(make_float2(b.z, b.w));
  return u.v;
}

// K1: dinv[i] = rsqrt(1 + sum_j adj[i][j])   (the +1 is the self-loop)
__global__ __launch_bounds__(256) void k_rowsum(const float* __restrict__ adj,
                                                float* __restrict__ dinv) {
  const int row = blockIdx.x;
  const float4* p = (const float4*)(adj + (size_t)row * NN);
  const int t = threadIdx.x;
  float s = 0.f;
#pragma unroll
  for (int j = 0; j < 16; ++j) {
    float4 v = p[t + j * 256];
    s += (v.x + v.y) + (v.z + v.w);
  }
#pragma unroll
  for (int o = 32; o > 0; o >>= 1) s += __shfl_down(s, o, 64);
  __shared__ float red[4];
  if ((t & 63) == 0) red[t >> 6] = s;
  __syncthreads();
  if (t == 0) dinv[row] = rsqrtf(1.0f + red[0] + red[1] + red[2] + red[3]);
}

// K0: W[c][k] fp32 -> Wt bf16 blocked [k/8][c][k%8]  (B-fragment-friendly layout)
__global__ __launch_bounds__(256) void k_wt(const float* __restrict__ W,
                                            __hip_bfloat16* __restrict__ wt) {
  const int t = blockIdx.x * 256 + threadIdx.x;   // 16384 threads
  const int c = t & (COUT - 1);
  const int k8 = t >> 8;                          // 0..63
  const float* src = W + (size_t)c * KIN + k8 * 8;
  floatx4 a = *(const floatx4*)(src);
  floatx4 b = *(const floatx4*)(src + 4);
  short8 v = cvt_bf16x8(a, b);
  *(short8*)(wt + ((size_t)(k8 * COUT + c)) * 8) = v;
}

// GEMM: C[64 x 256 tile] = A(fp32, lda) x B(bf16 blocked [K/8][256][8])
//   PROD_G=true : g = bf16(dinv_row * (acc + bias_col)) -> gout, plus I-term
//                 dinv_row * g atomically into out.
//   PROD_G=false: atomicAdd(out, dinv_row * acc)   (split-K over blockIdx.z)
template <bool PROD_G>
__global__ __launch_bounds__(256) void k_gemm(
    const float* __restrict__ A, const __hip_bfloat16* __restrict__ B,
    const float* __restrict__ dinv, const float* __restrict__ bias,
    __hip_bfloat16* __restrict__ gout, float* __restrict__ out,
    int lda, int ksteps) {
  __shared__ float ldsA[64 * 32];               // 8 KB, xor-swizzled fp32 tile
  __shared__ __hip_bfloat16 ldsB[4 * 256 * 8];  // 16 KB, [kblk][col][8]

  const int tid = threadIdx.x;
  const int wave = tid >> 6;
  const int lane = tid & 63;
  const int quad = lane >> 4;
  const int l15 = lane & 15;

  const int i0 = blockIdx.x * 64;
  const int k0s = blockIdx.z * ksteps * 32;

  // A staging: 512 lane-loads of 16B, slot e holds A[e>>3][(e&7)^((e>>3)&7)]
  const float* pA[2];
  uint32_t offA[2];
#pragma unroll
  for (int r = 0; r < 2; ++r) {
    int e = r * 256 + tid;
    int arow = e >> 3, af = e & 7;
    int fg = af ^ (arow & 7);
    pA[r] = A + (size_t)(i0 + arow) * lda + (k0s + fg * 4);
    offA[r] = (uint32_t)((r * 256 + wave * 64) * 16);  // wave-uniform LDS base
  }
  // B staging: 1024 lane-loads of 16B, contiguous (blocked layout is contiguous)
  const __hip_bfloat16* pB[4];
  uint32_t offB[4];
#pragma unroll
  for (int r = 0; r < 4; ++r) {
    int e = r * 256 + tid;
    int kb = e >> 8, cl = e & 255;
    pB[r] = B + ((size_t)((k0s >> 3) + kb) * COUT + cl) * 8;
    offB[r] = (uint32_t)((r * 256 + wave * 64) * 16);
  }

  floatx4 acc[4][4];
#pragma unroll
  for (int a = 0; a < 4; ++a)
#pragma unroll
    for (int b = 0; b < 4; ++b) acc[a][b] = (floatx4){0.f, 0.f, 0.f, 0.f};

  for (int ks = 0; ks < ksteps; ++ks) {
#pragma unroll
    for (int r = 0; r < 2; ++r) llds16(pA[r], (char*)ldsA + offA[r]);
#pragma unroll
    for (int r = 0; r < 4; ++r) llds16(pB[r], (char*)ldsB + offB[r]);
#pragma unroll
    for (int r = 0; r < 2; ++r) pA[r] += 32;            // advance K by 32 fp32
#pragma unroll
    for (int r = 0; r < 4; ++r) pB[r] += 4 * COUT * 8;  // 4 k-blocks
    __syncthreads();

    short8 afr[4], bfr[4];
#pragma unroll
    for (int mt = 0; mt < 4; ++mt) {
      int arow = mt * 16 + l15;
      int g0 = (2 * quad) ^ (arow & 7);
      int g1 = (2 * quad + 1) ^ (arow & 7);
      floatx4 f0 = *(const floatx4*)(ldsA + arow * 32 + g0 * 4);
      floatx4 f1 = *(const floatx4*)(ldsA + arow * 32 + g1 * 4);
      afr[mt] = cvt_bf16x8(f0, f1);
    }
#pragma unroll
    for (int nt = 0; nt < 4; ++nt) {
      int ccol = wave * 64 + nt * 16 + l15;
      bfr[nt] = *(const short8*)((const char*)ldsB + quad * 4096 + ccol * 16);
    }
#pragma unroll
    for (int mt = 0; mt < 4; ++mt)
#pragma unroll
      for (int nt = 0; nt < 4; ++nt)
        acc[mt][nt] = __builtin_amdgcn_mfma_f32_16x16x32_bf16(afr[mt], bfr[nt],
                                                              acc[mt][nt], 0, 0, 0);
    __syncthreads();
  }

  // epilogue: D layout col = lane&15, row = quad*4 + reg
#pragma unroll
  for (int mt = 0; mt < 4; ++mt) {
    const int gi0 = i0 + mt * 16 + quad * 4;
    float dv[4];
#pragma unroll
    for (int r = 0; r < 4; ++r) dv[r] = dinv[gi0 + r];
#pragma unroll
    for (int nt = 0; nt < 4; ++nt) {
      const int gc = wave * 64 + nt * 16 + l15;
      if constexpr (PROD_G) {
        const float bb = bias[gc];
        union { ushort4 u4; __hip_bfloat16 h[4]; } pk;
#pragma unroll
        for (int r = 0; r < 4; ++r) {
          float v = (acc[mt][nt][r] + bb) * dv[r];  // g = dinv_j * (h + b)
          pk.h[r] = __float2bfloat16(v);
          atomicAdd(out + (size_t)(gi0 + r) * COUT + gc, dv[r] * v);  // I-term
        }
        *(ushort4*)(gout + ((size_t)(gi0 >> 3) * COUT + gc) * 8 + (gi0 & 7)) = pk.u4;
      } else {
#pragma unroll
        for (int r = 0; r < 4; ++r)
          atomicAdd(out + (size_t)(gi0 + r) * COUT + gc, acc[mt][nt][r] * dv[r]);
      }
    }
  }
}

extern "C" void kernel_launch(void* const* d_in, const int* in_sizes, int n_in,
                              void* d_out, int out_size, void* d_ws, size_t ws_size,
                              hipStream_t stream) {
  const float* x   = (const float*)d_in[0];  // [16384,512]
  const float* adj = (const float*)d_in[1];  // [16384,16384]
  const float* W   = (const float*)d_in[2];  // [256,512]
  const float* b   = (const float*)d_in[3];  // [256]
  float* out = (float*)d_out;                // [16384,256]

  char* ws = (char*)d_ws;
  float* dinv        = (float*)ws;                              // 64 KB
  __hip_bfloat16* wt = (__hip_bfloat16*)(ws + 65536);           // 256 KB
  __hip_bfloat16* g  = (__hip_bfloat16*)(ws + 65536 + 262144);  // 8 MB

  hipMemsetAsync(d_out, 0, (size_t)out_size * sizeof(float), stream);
  k_wt<<<64, 256, 0, stream>>>(W, wt);
  k_rowsum<<<16384, 256, 0, stream>>>(adj, dinv);
  // g = bf16(dinv * (x W^T + b)) ; also adds I-term into out
  k_gemm<true><<<dim3(256, 1, 1), 256, 0, stream>>>(x, wt, dinv, b, g, out,
                                                    KIN, KIN / 32);
  // out += dinv_i * (A @ g), split-K=4
  k_gemm<false><<<dim3(256, 1, 4), 256, 0, stream>>>(adj, g, dinv, nullptr,
                                                     nullptr, out, NN, NN / (4 * 32));
}